// Round 1
// baseline (185.429 us; speedup 1.0000x reference)
//
#include <hip/hip_runtime.h>
#include <math.h>

#define WS 21
#define KWIN 43            // 2*WS+1
#define H 128
#define W 128
#define B 2
#define C 3
#define HW (H * W)
#define CHW (C * H * W)
#define NPIX (B * H * W)   // 32768
#define SIGMA_COLOR 50.0f
#define SIGMA_SPACE (1.0f / 98.0f)
#define NSPLIT 8

__device__ __forceinline__ int reflect_idx(int t, int n) {
    // numpy/jnp 'reflect' (no edge repeat): -k -> k, (n-1)+k -> (n-1)-k
    if (t < 0) t = -t;
    if (t > n - 1) t = 2 * (n - 1) - t;
    return t;
}

// ---------------- Kernel 1: edge responses + m_large mask ----------------
__global__ __launch_bounds__(256)
void edge_mask_kernel(const float* __restrict__ orig,
                      const float* __restrict__ smooth,
                      float* __restrict__ mlarge) {
    int idx = blockIdx.x * blockDim.x + threadIdx.x;
    if (idx >= NPIX) return;
    int b  = idx / HW;
    int hw = idx % HW;
    int h  = hw / W;
    int w  = hw % W;

    int hm = reflect_idx(h - 1, H), hp = reflect_idx(h + 1, H);
    int wm = reflect_idx(w - 1, W), wp = reflect_idx(w + 1, W);

    float eo = 0.f, es = 0.f;
#pragma unroll
    for (int c = 0; c < C; ++c) {
        const float* po = orig   + b * CHW + c * HW;
        const float* ps = smooth + b * CHW + c * HW;
        {
            float a00 = po[hm * W + wm], a01 = po[hm * W + w], a02 = po[hm * W + wp];
            float a10 = po[h  * W + wm],                        a12 = po[h  * W + wp];
            float a20 = po[hp * W + wm], a21 = po[hp * W + w], a22 = po[hp * W + wp];
            float gx = (a02 - a00) + 2.f * (a12 - a10) + (a22 - a20);
            float gy = (a20 - a00) + 2.f * (a21 - a01) + (a22 - a02);
            eo += sqrtf(gx * gx + gy * gy);
        }
        {
            float a00 = ps[hm * W + wm], a01 = ps[hm * W + w], a02 = ps[hm * W + wp];
            float a10 = ps[h  * W + wm],                        a12 = ps[h  * W + wp];
            float a20 = ps[hp * W + wm], a21 = ps[hp * W + w], a22 = ps[hp * W + wp];
            float gx = (a02 - a00) + 2.f * (a12 - a10) + (a22 - a20);
            float gy = (a20 - a00) + 2.f * (a21 - a01) + (a22 - a02);
            es += sqrtf(gx * gx + gy * gy);
        }
    }
    float m = ((eo < 20.0f) && ((es - eo) > 10.0f)) ? 1.0f : 0.0f;
    mlarge[idx] = m;
}

// ---------------- Kernel 2: main accumulation ----------------
__global__ __launch_bounds__(256)
void smooth_loss_kernel(const float* __restrict__ orig,
                        const float* __restrict__ smooth,
                        const float* __restrict__ mlarge,
                        float* __restrict__ out) {
    __shared__ float wtab[KWIN];
    __shared__ float red[4];

    int t = threadIdx.x;
    if (t < KWIN) {
        int k = t - WS;
        wtab[t] = __expf(-SIGMA_SPACE * (float)(k * k));
    }
    __syncthreads();

    int gid   = blockIdx.x * blockDim.x + t;   // 0 .. 262143
    int pix   = gid & (NPIX - 1);
    int split = gid >> 15;                     // 0 .. 7
    int b  = pix >> 14;
    int hw = pix & (HW - 1);
    int h  = hw >> 7;
    int w  = hw & (W - 1);

    const float* ob = orig   + b * CHW;
    const float* sb = smooth + b * CHW;

    float s0 = sb[hw], s1 = sb[HW + hw], s2 = sb[2 * HW + hw];
    float o0 = ob[hw], o1 = ob[HW + hw], o2 = ob[2 * HW + hw];
    float m  = mlarge[pix];
    float ms = 1.0f - m;

    float acc = 0.f;

    for (int xi = split; xi < KWIN; xi += NSPLIT) {
        int x  = xi - WS;
        int hh = h + x;
        hh = (hh < 0) ? -hh : hh;
        hh = (hh > H - 1) ? 2 * (H - 1) - hh : hh;
        float wsx = wtab[xi];
        const float* orow = ob + hh * W;
        const float* srow = sb + hh * W;

        for (int yi = 0; yi < KWIN; ++yi) {
            int ww = w + yi - WS;
            ww = (ww < 0) ? -ww : ww;
            ww = (ww > W - 1) ? 2 * (W - 1) - ww : ww;

            float ss0 = srow[ww], ss1 = srow[HW + ww], ss2 = srow[2 * HW + ww];
            float os0 = orow[ww], os1 = orow[HW + ww], os2 = orow[2 * HW + ww];

            float d0 = fabsf(s0 - ss0);
            float d1 = fabsf(s1 - ss1);
            float d2 = fabsf(s2 - ss2);
            float e0 = o0 - os0, e1 = o1 - os1, e2 = o2 - os2;
            float sq = e0 * e0 + e1 * e1 + e2 * e2;
            float wr = __expf(-SIGMA_COLOR * sq);
            float dsq = d0 * d0 + d1 * d1 + d2 * d2;

            float p0 = (d0 > 0.f) ? exp2f(0.8f * __log2f(d0)) : 0.f;
            float p1 = (d1 > 0.f) ? exp2f(0.8f * __log2f(d1)) : 0.f;
            float p2 = (d2 > 0.f) ? exp2f(0.8f * __log2f(d2)) : 0.f;

            float wsw = wsx * wtab[yi];
            acc += m * wsw * dsq + ms * wr * (p0 + p1 + p2);
        }
    }

    // wave (64-lane) shuffle reduction, then cross-wave via LDS
#pragma unroll
    for (int off = 32; off > 0; off >>= 1) acc += __shfl_down(acc, off, 64);
    int lane = t & 63, wave = t >> 6;
    if (lane == 0) red[wave] = acc;
    __syncthreads();
    if (t == 0) {
        float s = red[0] + red[1] + red[2] + red[3];
        atomicAdd(out, s * (1.0f / (float)NPIX));
    }
}

extern "C" void kernel_launch(void* const* d_in, const int* in_sizes, int n_in,
                              void* d_out, int out_size, void* d_ws, size_t ws_size,
                              hipStream_t stream) {
    const float* orig   = (const float*)d_in[0];  // original_images (2,3,128,128)
    const float* smooth = (const float*)d_in[1];  // smooth_images   (2,3,128,128)
    float* out    = (float*)d_out;
    float* mlarge = (float*)d_ws;                 // NPIX floats = 128 KB

    hipMemsetAsync(out, 0, sizeof(float), stream);

    edge_mask_kernel<<<NPIX / 256, 256, 0, stream>>>(orig, smooth, mlarge);
    smooth_loss_kernel<<<(NPIX * NSPLIT) / 256, 256, 0, stream>>>(orig, smooth, mlarge, out);
}

// Round 2
// 116.468 us; speedup vs baseline: 1.5921x; 1.5921x over previous
//
#include <hip/hip_runtime.h>
#include <math.h>

#define WS 21
#define KWIN 43            // 2*WS+1
#define H 128
#define W 128
#define B 2
#define C 3
#define HW (H * W)
#define CHW (C * H * W)
#define NPIX (B * H * W)   // 32768
#define SIGMA_SPACE (1.0f / 98.0f)
#define NSPLIT 8
#define EXT 170            // extended row length: W + 2*WS
#define NELEM 2040         // 2 rows * 3 ch * EXT * 2 (s,o)

// wr * d^0.8 = exp2(0.8*log2|d| - 50*log2(e)*sq); 50*log2(e) = 72.13475204
#define NEG_SC_LOG2E 72.1347520445f

__device__ __forceinline__ int reflect_idx(int t, int n) {
    // numpy/jnp 'reflect' (no edge repeat)
    if (t < 0) t = -t;
    if (t > n - 1) t = 2 * (n - 1) - t;
    return t;
}

__global__ __launch_bounds__(256, 4)
void smooth_loss_kernel(const float* __restrict__ orig,
                        const float* __restrict__ smooth,
                        float* __restrict__ out) {
    // LDS: extended rows, interleaved (s,o) pairs:
    // float2 index = (half*3 + c)*EXT + e  ;  e = w + yi  (reflection pre-applied)
    __shared__ float extf[2048];   // 2040 used + 8 pad slots for invalid staging lanes
    __shared__ float wtab[KWIN];
    __shared__ float red[4];

    const int t     = threadIdx.x;
    const int split = blockIdx.x & 7;          // xi-slice
    const int rp    = (blockIdx.x >> 3) & 63;  // row pair
    const int b     = blockIdx.x >> 9;
    const int h0    = rp * 2;
    const int w     = t & 127;
    const int half  = t >> 7;
    const int h     = h0 + half;

    if (t < KWIN) {
        int k = t - WS;
        wtab[t] = __expf(-SIGMA_SPACE * (float)(k * k));
    }

    const float* ob = orig   + b * CHW;
    const float* sb = smooth + b * CHW;

    // ---- per-pixel mask (fused former edge kernel) ----
    float m;
    {
        int hm = reflect_idx(h - 1, H), hp = reflect_idx(h + 1, H);
        int wm = reflect_idx(w - 1, W), wp = reflect_idx(w + 1, W);
        float eo = 0.f, es = 0.f;
#pragma unroll
        for (int c = 0; c < C; ++c) {
            const float* po = ob + c * HW;
            const float* ps = sb + c * HW;
            {
                float a00 = po[hm * W + wm], a01 = po[hm * W + w], a02 = po[hm * W + wp];
                float a10 = po[h  * W + wm],                        a12 = po[h  * W + wp];
                float a20 = po[hp * W + wm], a21 = po[hp * W + w], a22 = po[hp * W + wp];
                float gx = (a02 - a00) + 2.f * (a12 - a10) + (a22 - a20);
                float gy = (a20 - a00) + 2.f * (a21 - a01) + (a22 - a02);
                eo += sqrtf(gx * gx + gy * gy);
            }
            {
                float a00 = ps[hm * W + wm], a01 = ps[hm * W + w], a02 = ps[hm * W + wp];
                float a10 = ps[h  * W + wm],                        a12 = ps[h  * W + wp];
                float a20 = ps[hp * W + wm], a21 = ps[hp * W + w], a22 = ps[hp * W + wp];
                float gx = (a02 - a00) + 2.f * (a12 - a10) + (a22 - a20);
                float gy = (a20 - a00) + 2.f * (a21 - a01) + (a22 - a02);
                es += sqrtf(gx * gx + gy * gy);
            }
        }
        m = ((eo < 20.0f) && ((es - eo) > 10.0f)) ? 1.0f : 0.0f;
    }

    // ---- per-thread staging descriptors (fixed across xi) ----
    // flat slot idx = (r*3 + c)*340 + e*2 + which   (which: 0=smooth, 1=orig)
    const float* sp_[8];
    int wb_[8];    // LDS float slot to write
    int rs_[8];    // which row-half this element belongs to
#pragma unroll
    for (int j = 0; j < 8; ++j) {
        int idx = t + 256 * j;
        if (idx < NELEM) {
            int r    = idx / 1020;
            int rem  = idx - 1020 * r;
            int c    = rem / 340;
            int rem2 = rem - 340 * c;
            int e    = rem2 >> 1;
            int which = rem2 & 1;
            int sc   = reflect_idx(e - WS, W);
            sp_[j] = (which ? ob : sb) + c * HW + sc;
            wb_[j] = idx;
            rs_[j] = r;
        } else {
            sp_[j] = sb;          // harmless
            wb_[j] = idx;         // pad slots 2040..2047
            rs_[j] = 0;
        }
    }

    // ---- prefetch first xi ----
    float v[8];
    {
        int x0  = split - WS;
        int hh0 = reflect_idx(h0 + x0, H);
        int hh1 = reflect_idx(h0 + 1 + x0, H);
#pragma unroll
        for (int j = 0; j < 8; ++j) v[j] = sp_[j][(rs_[j] ? hh1 : hh0) * W];
    }

    const float2* e2 = (const float2*)extf;
    const int cbase = 3 * half * EXT + w;   // float2 index base for this thread

    float s0c, s1c, s2c, o0c, o1c, o2c;
    {
        int hw = h * W + w;
        s0c = sb[hw]; s1c = sb[HW + hw]; s2c = sb[2 * HW + hw];
        o0c = ob[hw]; o1c = ob[HW + hw]; o2c = ob[2 * HW + hw];
    }

    float accL = 0.f;   // sum of wx*wy*dsq
    float accS = 0.f;   // sum of wr * (d0^.8 + d1^.8 + d2^.8)

    for (int xi = split; xi < KWIN; xi += NSPLIT) {
        __syncthreads();                       // previous compute done
#pragma unroll
        for (int j = 0; j < 8; ++j) extf[wb_[j]] = v[j];

        int xin = xi + NSPLIT;
        if (xin < KWIN) {                      // prefetch next row set during compute
            int xn  = xin - WS;
            int hh0 = reflect_idx(h0 + xn, H);
            int hh1 = reflect_idx(h0 + 1 + xn, H);
#pragma unroll
            for (int j = 0; j < 8; ++j) v[j] = sp_[j][(rs_[j] ? hh1 : hh0) * W];
        }
        __syncthreads();                       // staging visible

        float rowacc = 0.f;
#pragma unroll
        for (int yi = 0; yi < KWIN; ++yi) {
            float wy = wtab[yi];               // broadcast read
            float2 a0 = e2[cbase + 0 * EXT + yi];
            float2 a1 = e2[cbase + 1 * EXT + yi];
            float2 a2 = e2[cbase + 2 * EXT + yi];
            float d0 = s0c - a0.x, g0 = o0c - a0.y;
            float d1 = s1c - a1.x, g1 = o1c - a1.y;
            float d2 = s2c - a2.x, g2 = o2c - a2.y;
            float dsq = fmaf(d0, d0, fmaf(d1, d1, d2 * d2));
            float sq  = fmaf(g0, g0, fmaf(g1, g1, g2 * g2));
            rowacc = fmaf(wy, dsq, rowacc);
            float tt = -NEG_SC_LOG2E * sq;
            float p0 = __builtin_amdgcn_exp2f(fmaf(0.8f, __builtin_amdgcn_logf(fabsf(d0)), tt));
            float p1 = __builtin_amdgcn_exp2f(fmaf(0.8f, __builtin_amdgcn_logf(fabsf(d1)), tt));
            float p2 = __builtin_amdgcn_exp2f(fmaf(0.8f, __builtin_amdgcn_logf(fabsf(d2)), tt));
            accS += (p0 + p1) + p2;
        }
        float xf = (float)(xi - WS);
        float wx = __expf(-SIGMA_SPACE * xf * xf);
        accL = fmaf(wx, rowacc, accL);
    }

    float r = m * accL + (1.0f - m) * accS;

    // wave (64) shuffle reduce, then cross-wave
#pragma unroll
    for (int off = 32; off > 0; off >>= 1) r += __shfl_down(r, off, 64);
    int lane = t & 63, wave = t >> 6;
    if (lane == 0) red[wave] = r;
    __syncthreads();
    if (t == 0) {
        float s = red[0] + red[1] + red[2] + red[3];
        atomicAdd(out, s * (1.0f / (float)NPIX));
    }
}

extern "C" void kernel_launch(void* const* d_in, const int* in_sizes, int n_in,
                              void* d_out, int out_size, void* d_ws, size_t ws_size,
                              hipStream_t stream) {
    const float* orig   = (const float*)d_in[0];
    const float* smooth = (const float*)d_in[1];
    float* out = (float*)d_out;

    hipMemsetAsync(out, 0, sizeof(float), stream);
    smooth_loss_kernel<<<B * (H / 2) * NSPLIT, 256, 0, stream>>>(orig, smooth, out);
}